// Round 5
// baseline (69.351 us; speedup 1.0000x reference)
//
#include <hip/hip_runtime.h>

// TripletMarginLoss, N=512 anchors, D=128, labels in [0,64).
// loss = sum_{valid (i,j,k)} relu(dm[i,j]-dm[i,k]+1) / (count(> eps) + eps)
// valid(i,j,k) <=> j!=i && lab[j]==lab[i] && lab[k]!=lab[i]
//
// Locked-in findings (R0-R4):
//   - 256 MiB ws poison (~39.8 us, 85% HBM-write peak): unconditional tax.
//   - k1 is latency-bound: 1024-thr/block (4 waves/SIMD) + 24-load chains
//     is the best measured config (R4: -2.8 us vs R3).
//   - R1's +25 us single-kernel regression was the 512 per-block
//     __threadfence() L2 writeback-invalidates, NOT the atomics.
//
// Round-5: single dispatch. Cross-block combine via device-scope atomics
// ONLY (no threadfence): adds complete at the LLC (vmcnt(0)-ordered before
// the ticket), so the last ticket holder's LLC-coherent atomic reads see
// every block's contribution. Removes k2's serialized launch (~2-4 us).

#define TN 512
#define TD 128
#define TMARGIN 1.0f
#define TEPS 1e-8f

__device__ float        g_sum    = 0.f;
__device__ float        g_cnt    = 0.f;
__device__ unsigned int g_ticket = 0u;

// Block b handles anchors i0=2b, i1=2b+1. 1024 threads, 256 blocks.
__global__ __launch_bounds__(1024) void triplet_fused_kernel(
    const float* __restrict__ emb,
    const int* __restrict__ labels,
    float* __restrict__ out)
{
    __shared__ float d0[TN], d1[TN];    // dm rows for the two anchors
    __shared__ float pv0[TN], pv1[TN];  // positives: d[j] + margin
    __shared__ int   lab[TN];
    __shared__ int   npos0, npos1;
    __shared__ float red_s[16], red_c[16];

    const int b  = blockIdx.x;
    const int i0 = 2 * b;
    const int i1 = 2 * b + 1;
    const int t  = threadIdx.x;          // [0,1024)

    if (t < TN) lab[t] = labels[t];
    if (t == 0) { npos0 = 0; npos1 = 0; }

    // Anchor fragments in registers. Octet lane (oct,sub): chunks sub+8m,
    // m=0..3. Addresses repeat across octets -> cache broadcast.
    const int oct = t >> 3;              // [0,128): row within pass
    const int sub = t & 7;
    const float4* a0 = (const float4*)(emb + i0 * TD);
    const float4* a1 = (const float4*)(emb + i1 * TD);
    float4 w0[4], w1[4];
#pragma unroll
    for (int m = 0; m < 4; ++m) { w0[m] = a0[sub + 8 * m]; w1[m] = a1[sub + 8 * m]; }

    // dm rows: 4 passes x 128 rows. Octet oct handles row p*128+oct; lane
    // sub reads float4 chunks sub, sub+8, sub+16, sub+24 (128 B contiguous
    // per octet per m). Each load feeds both anchors' dot products.
#pragma unroll
    for (int p = 0; p < 4; ++p) {
        const int row = p * 128 + oct;
        const float4* rp = (const float4*)(emb + row * TD);
        float acc0 = 0.f, acc1 = 0.f;
#pragma unroll
        for (int m = 0; m < 4; ++m) {
            float4 v = rp[sub + 8 * m];
            acc0 += v.x * w0[m].x + v.y * w0[m].y + v.z * w0[m].z + v.w * w0[m].w;
            acc1 += v.x * w1[m].x + v.y * w1[m].y + v.z * w1[m].z + v.w * w1[m].w;
        }
        acc0 += __shfl_xor(acc0, 1);
        acc0 += __shfl_xor(acc0, 2);
        acc0 += __shfl_xor(acc0, 4);
        acc1 += __shfl_xor(acc1, 1);
        acc1 += __shfl_xor(acc1, 2);
        acc1 += __shfl_xor(acc1, 4);
        if (sub == 0) { d0[row] = acc0; d1[row] = acc1; }
    }
    __syncthreads();   // d0/d1, lab, npos visible

    // collect positives for both anchors: one j per thread (first 512)
    const int li0 = lab[i0], li1 = lab[i1];
    if (t < TN) {
        const int lj = lab[t];
        if (t != i0 && lj == li0) pv0[atomicAdd(&npos0, 1)] = d0[t] + TMARGIN;
        if (t != i1 && lj == li1) pv1[atomicAdd(&npos1, 1)] = d1[t] + TMARGIN;
    }
    __syncthreads();

    const int np0 = npos0, np1 = npos1;
    float lsum = 0.f, lcnt = 0.f;
    {
        // threads 0-511: anchor 0's negatives; 512-1023: anchor 1's.
        const int k  = t & (TN - 1);
        const int lk = lab[k];
        if (t < TN) {
            if (lk != li0) {
                const float dn = d0[k];
                for (int p = 0; p < np0; ++p) {
                    const float v = pv0[p] - dn;
                    if (v > 0.f)   lsum += v;
                    if (v > TEPS)  lcnt += 1.f;
                }
            }
        } else {
            if (lk != li1) {
                const float dn = d1[k];
                for (int p = 0; p < np1; ++p) {
                    const float v = pv1[p] - dn;
                    if (v > 0.f)   lsum += v;
                    if (v > TEPS)  lcnt += 1.f;
                }
            }
        }
    }

    // wave(64) shuffle reduction, then cross-wave via LDS
#pragma unroll
    for (int off = 32; off > 0; off >>= 1) {
        lsum += __shfl_down(lsum, off);
        lcnt += __shfl_down(lcnt, off);
    }
    const int wave = t >> 6;             // [0,16)
    if ((t & 63) == 0) { red_s[wave] = lsum; red_c[wave] = lcnt; }
    __syncthreads();

    if (t == 0) {
        float bs = 0.f, bc = 0.f;
#pragma unroll
        for (int wv = 0; wv < 16; ++wv) { bs += red_s[wv]; bc += red_c[wv]; }

        // Device-scope atomic combine at the LLC. NO threadfence (R1's
        // mistake): the returning adds are drained with vmcnt(0) before the
        // ticket increment, so LLC serialization orders {adds} < {ticket}.
        float o1 = atomicAdd(&g_sum, bs);
        float o2 = atomicAdd(&g_cnt, bc);
        asm volatile("s_waitcnt vmcnt(0)" :: "v"(o1), "v"(o2) : "memory");
        const unsigned int old = atomicAdd(&g_ticket, 1u);
        if (old == (unsigned int)(gridDim.x - 1)) {
            // last block: all other blocks' adds completed at the LLC
            // before their ticket increments -> these reads see them all.
            const float s = atomicAdd(&g_sum, 0.f);
            const float c = atomicAdd(&g_cnt, 0.f);
            out[0] = s / (c + TEPS);
            // restore the all-zeros invariant; safe across graph replays
            // because the next dispatch is stream-ordered after this one.
            atomicExch(&g_sum, 0.f);
            atomicExch(&g_cnt, 0.f);
            atomicExch(&g_ticket, 0u);
        }
    }
}

extern "C" void kernel_launch(void* const* d_in, const int* in_sizes, int n_in,
                              void* d_out, int out_size, void* d_ws, size_t ws_size,
                              hipStream_t stream) {
    const float* emb  = (const float*)d_in[0];
    const int* labels = (const int*)d_in[1];   // harness delivers integer inputs as int32
    float* out = (float*)d_out;
    (void)d_ws; (void)ws_size;

    triplet_fused_kernel<<<256, 1024, 0, stream>>>(emb, labels, out);
}

// Round 6
// 60.766 us; speedup vs baseline: 1.1413x; 1.1413x over previous
//
#include <hip/hip_runtime.h>

// TripletMarginLoss, N=512 anchors, D=128, labels in [0,64).
// loss = sum_{valid (i,j,k)} relu(dm[i,j]-dm[i,k]+1) / (count(> eps) + eps)
// valid(i,j,k) <=> j!=i && lab[j]==lab[i] && lab[k]!=lab[i]
//
// FINAL structure (R0-R5 evidence):
//   - Two dispatches; stream order is the grid barrier. Single-kernel
//     combine measured TWICE: with threadfence +25 us (R1), without +9 us
//     (R5, atomic/ticket LLC tail). Two dispatches win.
//   - 256 MiB ws poison (~39.8 us, 85% HBM-write peak): unconditional
//     harness tax; ws is free to use.
//   - k1 latency-bound: best = 256 blocks x 1024 thr (16 waves/CU),
//     2 anchors/block register reuse, 24-load chains (R4: 60.37 us).

#define TN 512
#define TD 128
#define TMARGIN 1.0f
#define TEPS 1e-8f

// Kernel 1: block b handles anchors i0=2b, i1=2b+1. 1024 threads.
__global__ __launch_bounds__(1024) void triplet_partial_kernel(
    const float* __restrict__ emb,
    const int* __restrict__ labels,
    float* __restrict__ ws)      // ws[2*b]=sum_b, ws[2*b+1]=count_b
{
    __shared__ float d0[TN], d1[TN];    // dm rows for the two anchors
    __shared__ float pv0[TN], pv1[TN];  // positives: d[j] + margin
    __shared__ int   lab[TN];
    __shared__ int   npos0, npos1;
    __shared__ float red_s[16], red_c[16];

    const int b  = blockIdx.x;
    const int i0 = 2 * b;
    const int i1 = 2 * b + 1;
    const int t  = threadIdx.x;          // [0,1024)

    if (t < TN) lab[t] = labels[t];
    if (t == 0) { npos0 = 0; npos1 = 0; }

    // Anchor fragments in registers. Octet lane (oct,sub): chunks sub+8m,
    // m=0..3. Addresses repeat across octets -> cache broadcast.
    const int oct = t >> 3;              // [0,128): row within pass
    const int sub = t & 7;
    const float4* a0 = (const float4*)(emb + i0 * TD);
    const float4* a1 = (const float4*)(emb + i1 * TD);
    float4 w0[4], w1[4];
#pragma unroll
    for (int m = 0; m < 4; ++m) { w0[m] = a0[sub + 8 * m]; w1[m] = a1[sub + 8 * m]; }

    // dm rows: 4 passes x 128 rows. Octet oct handles row p*128+oct; lane
    // sub reads float4 chunks sub, sub+8, sub+16, sub+24 (128 B contiguous
    // per octet per m). Each load feeds both anchors' dot products.
#pragma unroll
    for (int p = 0; p < 4; ++p) {
        const int row = p * 128 + oct;
        const float4* rp = (const float4*)(emb + row * TD);
        float acc0 = 0.f, acc1 = 0.f;
#pragma unroll
        for (int m = 0; m < 4; ++m) {
            float4 v = rp[sub + 8 * m];
            acc0 += v.x * w0[m].x + v.y * w0[m].y + v.z * w0[m].z + v.w * w0[m].w;
            acc1 += v.x * w1[m].x + v.y * w1[m].y + v.z * w1[m].z + v.w * w1[m].w;
        }
        acc0 += __shfl_xor(acc0, 1);
        acc0 += __shfl_xor(acc0, 2);
        acc0 += __shfl_xor(acc0, 4);
        acc1 += __shfl_xor(acc1, 1);
        acc1 += __shfl_xor(acc1, 2);
        acc1 += __shfl_xor(acc1, 4);
        if (sub == 0) { d0[row] = acc0; d1[row] = acc1; }
    }
    __syncthreads();   // d0/d1, lab, npos visible

    // collect positives for both anchors: one j per thread (first 512)
    const int li0 = lab[i0], li1 = lab[i1];
    if (t < TN) {
        const int lj = lab[t];
        if (t != i0 && lj == li0) pv0[atomicAdd(&npos0, 1)] = d0[t] + TMARGIN;
        if (t != i1 && lj == li1) pv1[atomicAdd(&npos1, 1)] = d1[t] + TMARGIN;
    }
    __syncthreads();

    const int np0 = npos0, np1 = npos1;
    float lsum = 0.f, lcnt = 0.f;
    {
        // threads 0-511: anchor 0's negatives; 512-1023: anchor 1's.
        // Wave-uniform split (t<512 at wave granularity).
        const int k  = t & (TN - 1);
        const int lk = lab[k];
        if (t < TN) {
            if (lk != li0) {
                const float dn = d0[k];
                for (int p = 0; p < np0; ++p) {
                    const float v = pv0[p] - dn;
                    if (v > 0.f)   lsum += v;
                    if (v > TEPS)  lcnt += 1.f;
                }
            }
        } else {
            if (lk != li1) {
                const float dn = d1[k];
                for (int p = 0; p < np1; ++p) {
                    const float v = pv1[p] - dn;
                    if (v > 0.f)   lsum += v;
                    if (v > TEPS)  lcnt += 1.f;
                }
            }
        }
    }

    // wave(64) shuffle reduction, then cross-wave via LDS
#pragma unroll
    for (int off = 32; off > 0; off >>= 1) {
        lsum += __shfl_down(lsum, off);
        lcnt += __shfl_down(lcnt, off);
    }
    const int wave = t >> 6;             // [0,16)
    if ((t & 63) == 0) { red_s[wave] = lsum; red_c[wave] = lcnt; }
    __syncthreads();

    if (t == 0) {
        float s = 0.f, c = 0.f;
#pragma unroll
        for (int wv = 0; wv < 16; ++wv) { s += red_s[wv]; c += red_c[wv]; }
        ws[2 * b]     = s;
        ws[2 * b + 1] = c;
    }
}

// Kernel 2: one wave reduces 256 {sum,count} pairs and finalizes.
__global__ __launch_bounds__(64) void triplet_reduce_kernel(
    const float* __restrict__ ws,
    float* __restrict__ out)
{
    const int t = threadIdx.x;
    float lsum = 0.f, lcnt = 0.f;
#pragma unroll
    for (int r = 0; r < 4; ++r) {
        const float2 p = ((const float2*)ws)[t + 64 * r];
        lsum += p.x;
        lcnt += p.y;
    }
#pragma unroll
    for (int off = 32; off > 0; off >>= 1) {
        lsum += __shfl_down(lsum, off);
        lcnt += __shfl_down(lcnt, off);
    }
    if (t == 0) out[0] = lsum / (lcnt + TEPS);
}

extern "C" void kernel_launch(void* const* d_in, const int* in_sizes, int n_in,
                              void* d_out, int out_size, void* d_ws, size_t ws_size,
                              hipStream_t stream) {
    const float* emb  = (const float*)d_in[0];
    const int* labels = (const int*)d_in[1];   // harness delivers integer inputs as int32
    float* out = (float*)d_out;
    float* ws  = (float*)d_ws;

    triplet_partial_kernel<<<256, 1024, 0, stream>>>(emb, labels, ws);
    triplet_reduce_kernel<<<1, 64, 0, stream>>>(ws, out);
}